// Round 11
// baseline (185.104 us; speedup 1.0000x reference)
//
#include <hip/hip_runtime.h>
#include <math.h>

// IDMForwardSim R16: fused dual-group anti-phase block. Evidence: serial-
// structure changes convert ~100% (tail-in-loop), pipe-demand cuts ~15%
// (R11/R12), TLP/stagger/priority null (R10/R14/R15), R9 dual-chain waves
// 1.8x denser. The wall is phase serialization: all waves do LDS->MFMA->gates
// in lockstep. Fix: one 896-thr block (14 waves = same residency as R13's
// 2x448), TWO 16-batch groups; each step = 2 barrier phases; in each phase
// one group MFMAs while the other runs gates (ph==grp ? MFMA : gates).
// One z/cx/cst/wb register set serves both groups (lifetimes interleave) so
// per-wave regs stay at the 128 budget. hS single-buffered per group (phase
// barrier orders write->read). Tail lag-1/2 on each group's wave 0 in its
// gate phase. Carries R13: fused-reciprocal gates, exp2 scales pre-folded,
// att_b in bp[100], params in LDS pS.

#define B_TOT 8192
#define T_STEPS 40
#define NB 32

typedef _Float16 f16;
typedef f16 f16x8 __attribute__((ext_vector_type(8)));
typedef float f32x4 __attribute__((ext_vector_type(4)));

__device__ __forceinline__ float rcpf(float x) { return __builtin_amdgcn_rcpf(x); }
__device__ __forceinline__ float ex2(float x)  { return __builtin_amdgcn_exp2f(x); }
__device__ __forceinline__ float sigf(float x)  { return rcpf(1.f + ex2(-1.44269504f * x)); }

// ws layout (bytes): whb f16[65536] @0 | wxb f16[65536] @131072 | bp f32[512] @262144

__global__ __launch_bounds__(256) void idm_prep(
    const float* __restrict__ Wx, const float* __restrict__ Wh,
    const float* __restrict__ bvec, const float* __restrict__ attw,
    const float* __restrict__ attB,
    f16* __restrict__ whb, f16* __restrict__ wxb,
    float* __restrict__ bp)
{
  int i = blockIdx.x * 256 + threadIdx.x;  // 0..65535, i = k*512 + n (coalesced reads)
  int k = i >> 9, n = i & 511;
  int g = n >> 7, j128 = n & 127;
  // pre-scale: sigmoid gates (zi,zf,zo) by log2(e), tanh gate (zg) by 2*log2(e)
  float sc = (g == 2) ? 2.88539008f : 1.44269504f;
  float vh = 0.f, vx = 0.f;
  if (j128 < 100) {
    int col = g * 100 + j128;
    if (k < 100)      { vh = Wh[k * 400 + col] * sc; vx = Wx[k * 400 + col] * sc; }
    else if (k < 102) { vh = Wx[k * 400 + col] * sc; }  // sdv rows folded into Wh-pad
  } else if (n == 100 && k < 100) {
    vh = attw[k];  // logit column stays UNSCALED (z[n=100] = h . att_W)
  }
  // dest B-frag index: tile=n>>4, kf=k>>5, l=((k>>3)&3)*16+(n&15), j=k&7
  int idx = (((n >> 4) * 4 + (k >> 5)) * 64 + (((k >> 3) & 3) * 16 + (n & 15))) * 8 + (k & 7);
  whb[idx] = (f16)vh;
  wxb[idx] = (f16)vx;
  if (i < 512) {
    int gg = i >> 7, jj = i & 127;
    float scb = (gg == 2) ? 2.88539008f : 1.44269504f;
    bp[i] = (jj < 100) ? bvec[gg * 100 + jj] * scb
                       : ((i == 100) ? attB[0] : 0.f);
  }
}

#define MM(z, a, g, kf) z = __builtin_amdgcn_mfma_f32_16x16x32_f16(a, wb[g][kf], z, 0, 0, 0)

// tail step for batch-in-block lb (gate-phase wave 0 of each group, lanes 0..15)
#define TAIL_STEP(tt, lb) {                                                    \
    int tt_ = (tt); int lb_ = (lb);                                            \
    float inv_dv = pS[0][lb_], des_tg = pS[1][lb_], min_jx = pS[2][lb_];       \
    float max_a = pS[3][lb_], inv2s = pS[4][lb_];                              \
    float2 s01 = *(const float2*)&sS[lb_][tt_][0];                             \
    float2 s23 = *(const float2*)&sS[lb_][tt_][2];                             \
    float2 s45 = *(const float2*)&sS[lb_][tt_][4];                             \
    float nf = nS[0][tt_][lb_], nm = nS[1][tt_][lb_];                          \
    float lg = logitS[tt_][lb_];                                               \
    ego_v += actT * 0.1f;                                                      \
    ego_x += ego_v * 0.1f + actT * 0.005f;                                     \
    float dxf = fminf(fmaxf(s23.x - ego_x, 0.5f), 1000.f);                     \
    float dgf = min_jx + fmaxf(0.f, des_tg * ego_v + ego_v * (ego_v - s01.x) * inv2s); \
    float rr = ego_v * inv_dv; float rr2 = rr * rr;                            \
    float qf = dgf * rcpf(dxf);                                                \
    float af_ = fminf(fmaxf(max_a * (1.f - rr2 * rr2 - qf * qf), -3.f), 3.f);  \
    float dxm = fminf(fmaxf(s23.y - ego_x, 0.5f), 1000.f);                     \
    float dgm = min_jx + fmaxf(0.f, des_tg * ego_v + ego_v * (ego_v - s01.y) * inv2s); \
    float qm = dgm * rcpf(dxm);                                                \
    float am_ = fminf(fmaxf(max_a * (1.f - rr2 * rr2 - qm * qm), -3.f), 3.f);  \
    float ef2 = s45.x * af_ + (1.f - s45.x) * nf;                              \
    float em2 = s45.y * am_ + (1.f - s45.y) * nm;                              \
    float att = sigf(5.f * lg);                                                \
    actT = (1.f - att) * ef2 + att * em2;                                      \
    accS[0][lb_][tt_] = actT;                                                  \
    accS[1][lb_][tt_] = att;                                                   \
  }

__global__ __launch_bounds__(896, 4) void idm_main(
    const float* __restrict__ z_att,
    const float* __restrict__ linear_W,
    const float* __restrict__ linear_b,
    const float* __restrict__ sdv_acts,
    const f16* __restrict__ whb, const f16* __restrict__ wxb,
    const float* __restrict__ bp,
    const float* __restrict__ idm_params,
    const float* __restrict__ idm_s,
    const float* __restrict__ noise_f,
    const float* __restrict__ noise_m,
    float* __restrict__ out)
{
  __shared__ f16   hS[2][16][136];       // [grp][batch][k] single-buffered (phase barrier orders)
  __shared__ f16   sdvS[T_STEPS][32][2];
  __shared__ float logitS[T_STEPS][32];  // [t][lb] lb<16 = A, >=16 = B
  __shared__ float sS[32][T_STEPS][6];
  __shared__ float nS[2][T_STEPS][32];
  __shared__ float accS[2][32][T_STEPS];
  __shared__ float pS[5][32];

  const int tid = threadIdx.x;
  const int w   = tid >> 6;              // 0..13
  const int grp = (w >= 7) ? 1 : 0;      // group A = waves 0..6, B = 7..13
  const int wv  = grp ? (w - 7) : w;     // j-tile within group, 0..6
  const int l  = tid & 63;
  const int lr = l & 15;
  const int lq = l >> 4;
  const int b0g = blockIdx.x * NB;
  const int jcol = 16 * wv + lr;

  // zero hS (pad rows must stay exact 0): 2*16*136 f16 = 2176 dwords
  for (int idx = tid; idx < 2176; idx += 896) ((unsigned*)hS)[idx] = 0u;
  // coalesced staging: sdv (2560 f), idm_s fields (10240 f), noise (2560 f)
  for (int idx = tid; idx < 2560; idx += 896) {
    float v = sdv_acts[(size_t)b0g * 80 + idx];
    int b = idx / 80, r = idx - b * 80;
    sdvS[r >> 1][b][r & 1] = (f16)v;
  }
  for (int idx = tid; idx < 10240; idx += 896) {
    int f = idx & 7;
    if (f != 0 && f != 3) {
      int b = idx / 320, rem = idx - b * 320, t = rem >> 3;
      sS[b][t][(f < 3) ? f - 1 : f - 2] = idm_s[(size_t)b0g * 320 + idx];
    }
  }
  for (int idx = tid; idx < 2560; idx += 896) {
    int which = idx >= 1280 ? 1 : 0;
    int r = idx - which * 1280;
    int t = r >> 5, i = r & 31;
    nS[which][t][i] = which ? noise_m[(size_t)t * B_TOT + b0g + i]
                            : noise_f[(size_t)t * B_TOT + b0g + i];
  }
  if (tid < 160) pS[tid % 5][tid / 5] = idm_params[(size_t)b0g * 5 + tid];
  __syncthreads();

  if (tid < 32) {
    pS[0][tid] = rcpf(pS[0][tid]);
    pS[4][tid] = 0.5f / sqrtf(pS[3][tid] * pS[4][tid]);
  }

  // h0 = att_proj for both groups (32 batches x 16 octs = 512 slots)
  if (tid >= 64 && tid < 576) {
    int s2 = tid - 64;
    int lb = s2 >> 4, oct = s2 & 15;
    float za[10];
    #pragma unroll
    for (int t2 = 0; t2 < 10; ++t2) za[t2] = z_att[(size_t)(b0g + lb) * 10 + t2];
    #pragma unroll
    for (int jj = 0; jj < 8; ++jj) {
      int j = oct * 8 + jj;
      if (j < 100) {
        float acc = linear_b[j];
        #pragma unroll
        for (int t2 = 0; t2 < 10; ++t2) acc = fmaf(za[t2], linear_W[t2 * 100 + j], acc);
        hS[lb >> 4][lb & 15][j] = (f16)acc;
      }
    }
  }
  if (tid < 64) hS[tid >> 5][(tid >> 1) & 15][100 + (tid & 1)] = sdvS[0][tid >> 1][tid & 1];
  __syncthreads();

  // Wx frags -> cx (per group from its own h0), then Wh frags
  f16x8 wb[4][4];
  #pragma unroll
  for (int g = 0; g < 4; ++g) {
    int tile = wv + 8 * g;
    #pragma unroll
    for (int kf = 0; kf < 4; ++kf)
      wb[g][kf] = *(const f16x8*)(wxb + ((size_t)(tile * 4 + kf) * 64 + l) * 8);
  }
  f32x4 cx[4];
  #pragma unroll
  for (int g = 0; g < 4; ++g) {
    float bpv = bp[(wv + 8 * g) * 16 + lr];
    f32x4 c = {bpv, bpv, bpv, bpv};
    cx[g] = c;
  }
  #pragma unroll
  for (int kf = 0; kf < 4; ++kf) {
    f16x8 a = *(const f16x8*)(&hS[grp][lr][kf * 32 + lq * 8]);
    #pragma unroll
    for (int g = 0; g < 4; ++g)
      cx[g] = __builtin_amdgcn_mfma_f32_16x16x32_f16(a, wb[g][kf], cx[g], 0, 0, 0);
  }
  #pragma unroll
  for (int g = 0; g < 4; ++g) {
    int tile = wv + 8 * g;
    #pragma unroll
    for (int kf = 0; kf < 4; ++kf)
      wb[g][kf] = *(const f16x8*)(whb + ((size_t)(tile * 4 + kf) * 64 + l) * 8);
  }

  float cst[4];
  #pragma unroll
  for (int r = 0; r < 4; ++r) cst[r] = (float)hS[grp][lq * 4 + r][jcol];

  // tail state (gate-phase wave 0 of each group, lanes 0..15)
  float ego_v = 0.f, ego_x = 0.f, actT = 0.f;
  if (wv == 0 && l < 16) {
    int b = b0g + grp * 16 + l;
    ego_v = idm_s[(size_t)b * 320 + 0];
    ego_x = idm_s[(size_t)b * 320 + 3];
  }

  // z carried across ONE barrier per half-iteration; one register set serves
  // both groups (A: def ph0/use ph1; B: def ph1/use next ph0 — interleaved).
  f32x4 z0, z1, z2, z3;

  for (int hi = 0; hi < 2 * T_STEPS; ++hi) {
    int ph = hi & 1, step = hi >> 1;
    if (ph == grp) {
      // ---- MFMA(step): z = cx + [h^step, sdv_step] @ Wh' ----
      f16x8 a0 = *(const f16x8*)(&hS[grp][lr][0  + lq * 8]);
      f16x8 a1 = *(const f16x8*)(&hS[grp][lr][32 + lq * 8]);
      f16x8 a2 = *(const f16x8*)(&hS[grp][lr][64 + lq * 8]);
      f16x8 a3 = *(const f16x8*)(&hS[grp][lr][96 + lq * 8]);
      z0 = cx[0]; z1 = cx[1]; z2 = cx[2]; z3 = cx[3];
      MM(z0,a0,0,0); MM(z1,a0,1,0); MM(z2,a0,2,0); MM(z3,a0,3,0);
      MM(z0,a1,0,1); MM(z1,a1,1,1); MM(z2,a1,2,1); MM(z3,a1,3,1);
      MM(z0,a2,0,2); MM(z1,a2,1,2); MM(z2,a2,2,2); MM(z3,a2,3,2);
      MM(z0,a3,0,3); MM(z1,a3,1,3); MM(z2,a3,2,3); MM(z3,a3,3,3);
      // logit for output step-1 (z col n=100 lives in tile 6, g=0, lane lr==4)
      if (wv == 6 && step > 0 && lr == 4) {
        #pragma unroll
        for (int r = 0; r < 4; ++r) logitS[step - 1][grp * 16 + lq * 4 + r] = z0[r];
      }
    } else {
      // ---- gates(gstep): consume z, write h^{gstep+1}; sdv top-up; tail ----
      int gstep = step - grp;   // A: step, B: step-1
      if (gstep >= 0) {
        #pragma unroll
        for (int r = 0; r < 4; ++r) {
          float e0 = ex2(-z0[r]);
          float e1 = ex2(-z1[r]);
          float e2 = fminf(ex2(z2[r]), 1e30f);
          float e3 = ex2(-z3[r]);
          float sf  = rcpf(1.f + e1);
          float itg = (e2 - 1.f) * rcpf((1.f + e0) * (1.f + e2));  // si*tg
          float cc  = fmaf(sf, cst[r], itg);
          float d   = fminf(ex2(2.88539008f * cc), 1e30f);
          float hh  = (d - 1.f) * rcpf((1.f + e3) * (1.f + d));    // so*tanh(cc)
          cst[r] = cc;
          if (jcol < 100) hS[grp][lq * 4 + r][jcol] = (f16)hh;
        }
        if (wv == 1 && l < 32 && gstep + 1 < T_STEPS)
          hS[grp][l >> 1][100 + (l & 1)] = sdvS[gstep + 1][grp * 16 + (l >> 1)][l & 1];
        if (wv == 0 && l < 16 && gstep >= 1) TAIL_STEP(gstep - 1, grp * 16 + l);
      }
    }
    __syncthreads();
  }

  // ---- epilogue ----
  // e1: A wave6 -> final logitA[39] from hA[40]; B: gates(39) -> hB[40], tail 38
  if (grp == 0) {
    if (wv == 6) {
      float bpv6 = bp[96 + lr];
      f32x4 zL = {bpv6, bpv6, bpv6, bpv6};
      #pragma unroll
      for (int kf = 0; kf < 4; ++kf) {
        f16x8 a = *(const f16x8*)(&hS[0][lr][kf * 32 + lq * 8]);
        zL = __builtin_amdgcn_mfma_f32_16x16x32_f16(a, wb[0][kf], zL, 0, 0, 0);
      }
      if (lr == 4) {
        #pragma unroll
        for (int r = 0; r < 4; ++r) logitS[T_STEPS - 1][lq * 4 + r] = zL[r];
      }
    }
  } else {
    // gates_B(39) from z of hi=79
    #pragma unroll
    for (int r = 0; r < 4; ++r) {
      float e0 = ex2(-z0[r]);
      float e1 = ex2(-z1[r]);
      float e2 = fminf(ex2(z2[r]), 1e30f);
      float e3 = ex2(-z3[r]);
      float sf  = rcpf(1.f + e1);
      float itg = (e2 - 1.f) * rcpf((1.f + e0) * (1.f + e2));
      float cc  = fmaf(sf, cst[r], itg);
      float d   = fminf(ex2(2.88539008f * cc), 1e30f);
      float hh  = (d - 1.f) * rcpf((1.f + e3) * (1.f + d));
      cst[r] = cc;
      if (jcol < 100) hS[1][lq * 4 + r][jcol] = (f16)hh;
    }
    if (wv == 0 && l < 16) TAIL_STEP(T_STEPS - 2, 16 + l);  // logitB[38] visible
  }
  __syncthreads();
  // e2: B wave6 -> final logitB[39] from hB[40]; A tail 39
  if (grp == 1 && wv == 6) {
    float bpv6 = bp[96 + lr];
    f32x4 zL = {bpv6, bpv6, bpv6, bpv6};
    #pragma unroll
    for (int kf = 0; kf < 4; ++kf) {
      f16x8 a = *(const f16x8*)(&hS[1][lr][kf * 32 + lq * 8]);
      zL = __builtin_amdgcn_mfma_f32_16x16x32_f16(a, wb[0][kf], zL, 0, 0, 0);
    }
    if (lr == 4) {
      #pragma unroll
      for (int r = 0; r < 4; ++r) logitS[T_STEPS - 1][16 + lq * 4 + r] = zL[r];
    }
  }
  if (grp == 0 && wv == 0 && l < 16) TAIL_STEP(T_STEPS - 1, l);
  __syncthreads();
  // e3: B tail 39
  if (grp == 1 && wv == 0 && l < 16) TAIL_STEP(T_STEPS - 1, 16 + l);
  __syncthreads();

  // coalesced output store: 1280 floats per output per block
  if (tid < 320) {
    f32x4 va = ((const f32x4*)&accS[0][0][0])[tid];
    f32x4 vt = ((const f32x4*)&accS[1][0][0])[tid];
    *(f32x4*)(out + (size_t)b0g * T_STEPS + tid * 4) = va;
    *(f32x4*)(out + (size_t)B_TOT * T_STEPS + (size_t)b0g * T_STEPS + tid * 4) = vt;
  }
}

extern "C" void kernel_launch(void* const* d_in, const int* in_sizes, int n_in,
                              void* d_out, int out_size, void* d_ws, size_t ws_size,
                              hipStream_t stream) {
  const float* z_att      = (const float*)d_in[0];
  const float* idm_params = (const float*)d_in[2];
  const float* idm_s      = (const float*)d_in[3];
  const float* sdv_acts   = (const float*)d_in[4];
  const float* linear_W   = (const float*)d_in[5];
  const float* linear_b   = (const float*)d_in[6];
  const float* lstm_Wx    = (const float*)d_in[7];
  const float* lstm_Wh    = (const float*)d_in[8];
  const float* lstm_b     = (const float*)d_in[9];
  const float* att_W      = (const float*)d_in[10];
  const float* att_b      = (const float*)d_in[11];
  const float* noise_f    = (const float*)d_in[12];
  const float* noise_m    = (const float*)d_in[13];
  float* out = (float*)d_out;

  f16*   whb = (f16*)d_ws;
  f16*   wxb = (f16*)((char*)d_ws + 131072);
  float* bp  = (float*)((char*)d_ws + 262144);

  idm_prep<<<256, 256, 0, stream>>>(lstm_Wx, lstm_Wh, lstm_b, att_W, att_b,
                                    whb, wxb, bp);
  idm_main<<<B_TOT / NB, 896, 0, stream>>>(z_att, linear_W, linear_b, sdv_acts,
                                           whb, wxb, bp,
                                           idm_params, idm_s,
                                           noise_f, noise_m, out);
}

// Round 12
// 172.482 us; speedup vs baseline: 1.0732x; 1.0732x over previous
//
#include <hip/hip_runtime.h>
#include <math.h>

// IDMForwardSim R17: dedicated tail wave with LDS state. R16 (code-enforced
// anti-phase) confirmed the phase-overlap family dies on register pressure:
// z across a barrier = +32 live regs = spills (WRITE 15MB). Dropped.
// Remaining untested lever: the straggler tax — wave 0 runs gates + ~300cy
// tail chain while 13 waves wait at the barrier (R10's 8th-wave test was
// poisoned by lambda scratch; R13's wave-0 tail pushed gates+tail union over
// the 128-reg budget = persistent 1.8MB scratch). Fix: 512-thr blocks
// (8 waves, NB=16, 2 blocks/CU = 16 waves/CU at 128 regs); waves 0..6 run the
// pure R8 compute loop (clean register file, no spills); wave 7 does sdv
// top-up (lanes 32..63) + lag-2 tail (lanes 0..15) with ego_v/ego_x/actT in
// LDS tS[3][16] — zero persistent tail registers, so union liveness cannot
// spill the compute waves. Carries R13: fused-reciprocal gates, exp2 scales
// pre-folded, att_b in bp[100], params in LDS pS.

#define B_TOT 8192
#define T_STEPS 40
#define NB 16

typedef _Float16 f16;
typedef f16 f16x8 __attribute__((ext_vector_type(8)));
typedef float f32x4 __attribute__((ext_vector_type(4)));

__device__ __forceinline__ float rcpf(float x) { return __builtin_amdgcn_rcpf(x); }
__device__ __forceinline__ float ex2(float x)  { return __builtin_amdgcn_exp2f(x); }
__device__ __forceinline__ float sigf(float x)  { return rcpf(1.f + ex2(-1.44269504f * x)); }

// ws layout (bytes): whb f16[65536] @0 | wxb f16[65536] @131072 | bp f32[512] @262144

__global__ __launch_bounds__(256) void idm_prep(
    const float* __restrict__ Wx, const float* __restrict__ Wh,
    const float* __restrict__ bvec, const float* __restrict__ attw,
    const float* __restrict__ attB,
    f16* __restrict__ whb, f16* __restrict__ wxb,
    float* __restrict__ bp)
{
  int i = blockIdx.x * 256 + threadIdx.x;  // 0..65535, i = k*512 + n (coalesced reads)
  int k = i >> 9, n = i & 511;
  int g = n >> 7, j128 = n & 127;
  // pre-scale: sigmoid gates (zi,zf,zo) by log2(e), tanh gate (zg) by 2*log2(e)
  float sc = (g == 2) ? 2.88539008f : 1.44269504f;
  float vh = 0.f, vx = 0.f;
  if (j128 < 100) {
    int col = g * 100 + j128;
    if (k < 100)      { vh = Wh[k * 400 + col] * sc; vx = Wx[k * 400 + col] * sc; }
    else if (k < 102) { vh = Wx[k * 400 + col] * sc; }  // sdv rows folded into Wh-pad
  } else if (n == 100 && k < 100) {
    vh = attw[k];  // logit column stays UNSCALED (z[n=100] = h . att_W)
  }
  // dest B-frag index: tile=n>>4, kf=k>>5, l=((k>>3)&3)*16+(n&15), j=k&7
  int idx = (((n >> 4) * 4 + (k >> 5)) * 64 + (((k >> 3) & 3) * 16 + (n & 15))) * 8 + (k & 7);
  whb[idx] = (f16)vh;
  wxb[idx] = (f16)vx;
  if (i < 512) {
    int gg = i >> 7, jj = i & 127;
    float scb = (gg == 2) ? 2.88539008f : 1.44269504f;
    // bp[100] carries att_b (logit column bias); other pad cols stay 0
    bp[i] = (jj < 100) ? bvec[gg * 100 + jj] * scb
                       : ((i == 100) ? attB[0] : 0.f);
  }
}

#define MM(z, a, g, kf) z = __builtin_amdgcn_mfma_f32_16x16x32_f16(a, wb[g][kf], z, 0, 0, 0)

// tail step (wave 7, lanes 0..15). Params from pS, operands from LDS;
// ego_v/ego_x/actT are surrounding locals loaded from/stored to tS.
#define TAIL_STEP(tt) {                                                        \
    int tt_ = (tt);                                                            \
    float inv_dv = pS[0][l], des_tg = pS[1][l], min_jx = pS[2][l];             \
    float max_a = pS[3][l], inv2s = pS[4][l];                                  \
    float2 s01 = *(const float2*)&sS[l][tt_][0];                               \
    float2 s23 = *(const float2*)&sS[l][tt_][2];                               \
    float2 s45 = *(const float2*)&sS[l][tt_][4];                               \
    float nf = nS[0][tt_][l], nm = nS[1][tt_][l];                              \
    float lg = logitS[tt_][l];                                                 \
    ego_v += actT * 0.1f;                                                      \
    ego_x += ego_v * 0.1f + actT * 0.005f;                                     \
    float dxf = fminf(fmaxf(s23.x - ego_x, 0.5f), 1000.f);                     \
    float dgf = min_jx + fmaxf(0.f, des_tg * ego_v + ego_v * (ego_v - s01.x) * inv2s); \
    float rr = ego_v * inv_dv; float rr2 = rr * rr;                            \
    float qf = dgf * rcpf(dxf);                                                \
    float af_ = fminf(fmaxf(max_a * (1.f - rr2 * rr2 - qf * qf), -3.f), 3.f);  \
    float dxm = fminf(fmaxf(s23.y - ego_x, 0.5f), 1000.f);                     \
    float dgm = min_jx + fmaxf(0.f, des_tg * ego_v + ego_v * (ego_v - s01.y) * inv2s); \
    float qm = dgm * rcpf(dxm);                                                \
    float am_ = fminf(fmaxf(max_a * (1.f - rr2 * rr2 - qm * qm), -3.f), 3.f);  \
    float ef2 = s45.x * af_ + (1.f - s45.x) * nf;                              \
    float em2 = s45.y * am_ + (1.f - s45.y) * nm;                              \
    float att = sigf(5.f * lg);                                                \
    actT = (1.f - att) * ef2 + att * em2;                                      \
    accS[0][l][tt_] = actT;                                                    \
    accS[1][l][tt_] = att;                                                     \
  }

// load/run/store wrapper: tail state lives in LDS, zero persistent registers
#define TAIL_RUN(tt) {                                                         \
    float ego_v = tS[0][l], ego_x = tS[1][l], actT = tS[2][l];                 \
    TAIL_STEP(tt);                                                             \
    tS[0][l] = ego_v; tS[1][l] = ego_x; tS[2][l] = actT;                       \
  }

__global__ __launch_bounds__(512, 4) void idm_main(
    const float* __restrict__ z_att,
    const float* __restrict__ linear_W,
    const float* __restrict__ linear_b,
    const float* __restrict__ sdv_acts,
    const f16* __restrict__ whb, const f16* __restrict__ wxb,
    const float* __restrict__ bp,
    const float* __restrict__ idm_params,
    const float* __restrict__ idm_s,
    const float* __restrict__ noise_f,
    const float* __restrict__ noise_m,
    float* __restrict__ out)
{
  __shared__ f16   hS[2][16][136];       // [buf][batch][k] 0..99 h, 100..101 sdv, pad 0
  __shared__ f16   sdvS[T_STEPS][16][2];
  __shared__ float logitS[T_STEPS][16];
  __shared__ float sS[16][T_STEPS][6];   // idm_s fields 1,2,4,5,6,7
  __shared__ float nS[2][T_STEPS][16];   // noise_f / noise_m
  __shared__ float accS[2][16][T_STEPS]; // act, att
  __shared__ float pS[5][16];            // inv_dv, des_tg, min_jx, max_a, inv2s
  __shared__ float tS[3][16];            // tail state: ego_v, ego_x, act

  const int tid = threadIdx.x;
  const int w  = tid >> 6;   // 0..6 j-tile, 7 = tail/service wave
  const int l  = tid & 63;
  const int lr = l & 15;
  const int lq = l >> 4;
  const int b0g = blockIdx.x * NB;
  const int jcol = 16 * w + lr;
  const bool tail_lane = (w == 7) && (l < 16);

  // zero hS (pad rows must stay exact 0)
  for (int idx = tid; idx < 2176; idx += 512) ((unsigned*)hS)[idx] = 0u;
  // coalesced staging: sdv (1280 f), idm_s fields (5120 f), noise (1280 f)
  for (int idx = tid; idx < 1280; idx += 512) {
    float v = sdv_acts[(size_t)b0g * 80 + idx];
    int b = idx / 80, r = idx - b * 80;
    sdvS[r >> 1][b][r & 1] = (f16)v;
  }
  for (int idx = tid; idx < 5120; idx += 512) {
    int f = idx & 7;
    if (f != 0 && f != 3) {
      int b = idx / 320, rem = idx - b * 320, t = rem >> 3;
      sS[b][t][(f < 3) ? f - 1 : f - 2] = idm_s[(size_t)b0g * 320 + idx];
    }
  }
  for (int idx = tid; idx < 1280; idx += 512) {
    int which = idx >= 640 ? 1 : 0;
    int r = idx - which * 640;
    int t = r >> 4, i = r & 15;
    nS[which][t][i] = which ? noise_m[(size_t)t * B_TOT + b0g + i]
                            : noise_f[(size_t)t * B_TOT + b0g + i];
  }
  // params: 80 consecutive floats, coalesced; pS[j][b] = idm_params[(b0g+b)*5+j]
  if (tid < 80) pS[tid % 5][tid / 5] = idm_params[(size_t)b0g * 5 + tid];
  __syncthreads();

  // in-place transform + tail-state init (LDS-resident)
  if (tid < 16) {
    pS[0][tid] = rcpf(pS[0][tid]);
    pS[4][tid] = 0.5f / sqrtf(pS[3][tid] * pS[4][tid]);
    tS[0][tid] = idm_s[(size_t)(b0g + tid) * 320 + 0];
    tS[1][tid] = idm_s[(size_t)(b0g + tid) * 320 + 3];
    tS[2][tid] = 0.f;
  }

  // h0 = att_proj into hS[0]
  if (tid >= 64 && tid < 320) {
    int s2 = tid - 64;
    int b = s2 >> 4, oct = s2 & 15;
    float za[10];
    #pragma unroll
    for (int t2 = 0; t2 < 10; ++t2) za[t2] = z_att[(b0g + b) * 10 + t2];
    #pragma unroll
    for (int jj = 0; jj < 8; ++jj) {
      int j = oct * 8 + jj;
      if (j < 100) {
        float acc = linear_b[j];
        #pragma unroll
        for (int t2 = 0; t2 < 10; ++t2) acc = fmaf(za[t2], linear_W[t2 * 100 + j], acc);
        hS[0][b][j] = (f16)acc;
      }
    }
  }
  if (tid < 32) hS[0][tid >> 1][100 + (tid & 1)] = sdvS[0][tid >> 1][tid & 1];
  __syncthreads();

  // compute waves only: Wx frags -> cx, then Wh frags (loop-invariant in regs)
  f16x8 wb[4][4];
  f32x4 cx[4];
  float cst[4];
  if (w < 7) {
    #pragma unroll
    for (int g = 0; g < 4; ++g) {
      int tile = w + 8 * g;
      #pragma unroll
      for (int kf = 0; kf < 4; ++kf)
        wb[g][kf] = *(const f16x8*)(wxb + ((size_t)(tile * 4 + kf) * 64 + l) * 8);
    }
    #pragma unroll
    for (int g = 0; g < 4; ++g) {
      float bpv = bp[(w + 8 * g) * 16 + lr];
      f32x4 c = {bpv, bpv, bpv, bpv};
      cx[g] = c;
    }
    #pragma unroll
    for (int kf = 0; kf < 4; ++kf) {
      f16x8 a = *(const f16x8*)(&hS[0][lr][kf * 32 + lq * 8]);
      #pragma unroll
      for (int g = 0; g < 4; ++g)
        cx[g] = __builtin_amdgcn_mfma_f32_16x16x32_f16(a, wb[g][kf], cx[g], 0, 0, 0);
    }
    #pragma unroll
    for (int g = 0; g < 4; ++g) {
      int tile = w + 8 * g;
      #pragma unroll
      for (int kf = 0; kf < 4; ++kf)
        wb[g][kf] = *(const f16x8*)(whb + ((size_t)(tile * 4 + kf) * 64 + l) * 8);
    }
    #pragma unroll
    for (int r = 0; r < 4; ++r) cst[r] = (float)hS[0][lq * 4 + r][jcol];
  }

  int p = 0;
  for (int t = 0; t < T_STEPS; ++t) {
    if (w < 7) {
      // A-frags for [h^{(t)}, sdv_t]
      f16x8 a0 = *(const f16x8*)(&hS[p][lr][0  + lq * 8]);
      f16x8 a1 = *(const f16x8*)(&hS[p][lr][32 + lq * 8]);
      f16x8 a2 = *(const f16x8*)(&hS[p][lr][64 + lq * 8]);
      f16x8 a3 = *(const f16x8*)(&hS[p][lr][96 + lq * 8]);
      f32x4 z0 = cx[0], z1 = cx[1], z2 = cx[2], z3 = cx[3];
      MM(z0,a0,0,0); MM(z1,a0,1,0); MM(z2,a0,2,0); MM(z3,a0,3,0);
      MM(z0,a1,0,1); MM(z1,a1,1,1); MM(z2,a1,2,1); MM(z3,a1,3,1);
      MM(z0,a2,0,2); MM(z1,a2,1,2); MM(z2,a2,2,2); MM(z3,a2,3,2);
      MM(z0,a3,0,3); MM(z1,a3,1,3); MM(z2,a3,2,3); MM(z3,a3,3,3);

      // logit for output t-1: z col n=100 (tile 6 = wave 6 g=0, lane lr==4);
      // includes att_b via bp[100] folded into cx
      if (w == 6 && t > 0 && lr == 4) {
        #pragma unroll
        for (int r = 0; r < 4; ++r) logitS[t - 1][lq * 4 + r] = z0[r];
      }

      // gates with fused reciprocals: si*tg = (e2-1)/((1+e0)(1+e2)),
      // so*tanh(cc) = (d-1)/((1+e3)(1+d)); overflow paths -> 0, no NaN.
      #pragma unroll
      for (int r = 0; r < 4; ++r) {
        float e0 = ex2(-z0[r]);
        float e1 = ex2(-z1[r]);
        float e2 = fminf(ex2(z2[r]), 1e30f);
        float e3 = ex2(-z3[r]);
        float sf  = rcpf(1.f + e1);
        float itg = (e2 - 1.f) * rcpf((1.f + e0) * (1.f + e2));  // si*tg
        float cc  = fmaf(sf, cst[r], itg);
        float d   = fminf(ex2(2.88539008f * cc), 1e30f);
        float hh  = (d - 1.f) * rcpf((1.f + e3) * (1.f + d));    // so*tanh(cc)
        cst[r] = cc;
        if (jcol < 100) hS[p ^ 1][lq * 4 + r][jcol] = (f16)hh;
      }
    } else {
      // wave 7 (service wave): sdv top-up on lanes 32..63, tail on lanes 0..15
      if (t + 1 < T_STEPS && l >= 32) {
        int ll = l - 32;
        hS[p ^ 1][ll >> 1][100 + (ll & 1)] = sdvS[t + 1][ll >> 1][ll & 1];
      }
      if (l < 16 && t >= 2) TAIL_RUN(t - 2);
    }
    __syncthreads();  // single barrier per step
    p ^= 1;
  }

  // final logit (t = T-1) from h^{(T)} in hS[p]: 4 MFMA on wave 6's gate-0
  // tile, seeded with bp (att_b at col 100). Wave 7 runs tail 38 in parallel
  // (logit[38] was written during step t=39, before the last loop barrier).
  if (w == 6) {
    float bpv6 = bp[96 + lr];
    f32x4 zL = {bpv6, bpv6, bpv6, bpv6};
    #pragma unroll
    for (int kf = 0; kf < 4; ++kf) {
      f16x8 a = *(const f16x8*)(&hS[p][lr][kf * 32 + lq * 8]);
      zL = __builtin_amdgcn_mfma_f32_16x16x32_f16(a, wb[0][kf], zL, 0, 0, 0);
    }
    if (lr == 4) {
      #pragma unroll
      for (int r = 0; r < 4; ++r) logitS[T_STEPS - 1][lq * 4 + r] = zL[r];
    }
  }
  if (tail_lane) TAIL_RUN(T_STEPS - 2);
  __syncthreads();
  if (tail_lane) TAIL_RUN(T_STEPS - 1);
  __syncthreads();

  // coalesced output store: 640 floats per output
  if (tid < 160) {
    f32x4 va = ((const f32x4*)&accS[0][0][0])[tid];
    f32x4 vt = ((const f32x4*)&accS[1][0][0])[tid];
    *(f32x4*)(out + (size_t)b0g * T_STEPS + tid * 4) = va;
    *(f32x4*)(out + (size_t)B_TOT * T_STEPS + (size_t)b0g * T_STEPS + tid * 4) = vt;
  }
}

extern "C" void kernel_launch(void* const* d_in, const int* in_sizes, int n_in,
                              void* d_out, int out_size, void* d_ws, size_t ws_size,
                              hipStream_t stream) {
  const float* z_att      = (const float*)d_in[0];
  const float* idm_params = (const float*)d_in[2];
  const float* idm_s      = (const float*)d_in[3];
  const float* sdv_acts   = (const float*)d_in[4];
  const float* linear_W   = (const float*)d_in[5];
  const float* linear_b   = (const float*)d_in[6];
  const float* lstm_Wx    = (const float*)d_in[7];
  const float* lstm_Wh    = (const float*)d_in[8];
  const float* lstm_b     = (const float*)d_in[9];
  const float* att_W      = (const float*)d_in[10];
  const float* att_b      = (const float*)d_in[11];
  const float* noise_f    = (const float*)d_in[12];
  const float* noise_m    = (const float*)d_in[13];
  float* out = (float*)d_out;

  f16*   whb = (f16*)d_ws;
  f16*   wxb = (f16*)((char*)d_ws + 131072);
  float* bp  = (float*)((char*)d_ws + 262144);

  idm_prep<<<256, 256, 0, stream>>>(lstm_Wx, lstm_Wh, lstm_b, att_W, att_b,
                                    whb, wxb, bp);
  idm_main<<<B_TOT / NB, 512, 0, stream>>>(z_att, linear_W, linear_b, sdv_acts,
                                           whb, wxb, bp,
                                           idm_params, idm_s,
                                           noise_f, noise_m, out);
}